// Round 28
// baseline (834.946 us; speedup 1.0000x reference)
//
#include <hip/hip_runtime.h>
#include <hip/hip_bf16.h>

#define RC 64
#define SC 64
#define NLAYERS 30
#define TTILE 64

typedef __attribute__((ext_vector_type(8))) short bf16x8;
typedef __attribute__((ext_vector_type(4))) float f32x4;

__device__ __forceinline__ unsigned short f2bf(float f) {
    __hip_bfloat16 h = __float2bfloat16(f);
    return *reinterpret_cast<unsigned short*>(&h);
}
__device__ __forceinline__ float bf2f(unsigned short u) {
    unsigned int x = ((unsigned int)u) << 16;
    return *reinterpret_cast<float*>(&x);
}

// ---------- prep: gather weights into bf16 fragment-linear layout (verified r6) ----------
__global__ __launch_bounds__(256) void wn_prep(
    const float* __restrict__ dw, const float* __restrict__ rw,
    const float* __restrict__ skw, const float* __restrict__ db,
    const float* __restrict__ rb, const float* __restrict__ skb,
    unsigned short* __restrict__ pW1, unsigned short* __restrict__ pW2,
    float* __restrict__ pB1, float* __restrict__ pB2)
{
    const int i = blockIdx.x;
    const int tx = threadIdx.x;
    const int l = tx & 63;

    #pragma unroll
    for (int p = 0; p < 8; ++p) {
        int f = p * 4 + (tx >> 6);
        int w = f >> 3, nf = (f >> 2) & 1, ks = f & 3;
        int cpp = w * 32 + nf * 16 + (l & 15);
        int bb = cpp >> 4;
        int c1 = (bb & 1 ? 64 : 0) + (bb >> 1) * 16 + (cpp & 15);
        bf16x8 v;
        #pragma unroll
        for (int j = 0; j < 8; ++j) {
            int k = ks * 32 + (l >> 4) * 8 + j;
            int tap = (k < 64) ? 0 : 1;
            int kk = k & 63;
            v[j] = (short)f2bf(dw[(((size_t)i * 128 + c1) * 64 + kk) * 2 + tap]);
        }
        *(bf16x8*)&pW1[((size_t)(i * 32 + f) * 64 + l) * 8] = v;
    }

    #pragma unroll
    for (int p = 0; p < 4; ++p) {
        int f = p * 4 + (tx >> 6);
        int w = f >> 2, nf = (f >> 1) & 1, ks = f & 1;
        int cpp = w * 32 + nf * 16 + (l & 15);
        int bb = cpp >> 4;
        int c2 = (bb >> 1) * 16 + (cpp & 15);
        const float* src = (bb & 1) ? skw : rw;
        bf16x8 v;
        #pragma unroll
        for (int j = 0; j < 8; ++j) {
            int k = ks * 32 + (l >> 4) * 8 + j;
            v[j] = (short)f2bf(src[((size_t)i * 64 + c2) * 64 + k]);
        }
        *(bf16x8*)&pW2[((size_t)(i * 16 + f) * 64 + l) * 8] = v;
    }

    if (tx < 128) {
        int bb = tx >> 4, r = tx & 15;
        int c1 = (bb & 1 ? 64 : 0) + (bb >> 1) * 16 + r;
        pB1[i * 128 + tx] = db[i * 128 + c1];
        int c2 = (bb >> 1) * 16 + r;
        pB2[i * 128 + tx] = (bb & 1) ? skb[i * 64 + c2] : rb[i * 64 + c2];
    }
}

// ---------- start: h[b][t][c] bf16 t-major ----------
__global__ __launch_bounds__(256) void wn_start(
    const float* __restrict__ x, const float* __restrict__ sw,
    const float* __restrict__ sb, unsigned short* __restrict__ h, int T)
{
    int t = blockIdx.x * blockDim.x + threadIdx.x;
    int b = blockIdx.y;
    float xv = x[(size_t)b * T + t];
    unsigned int pk[32];
    #pragma unroll
    for (int c = 0; c < 64; c += 2) {
        float v0 = fmaf(sw[c], xv, sb[c]);
        float v1 = fmaf(sw[c + 1], xv, sb[c + 1]);
        pk[c >> 1] = (unsigned int)f2bf(v0) | ((unsigned int)f2bf(v1) << 16);
    }
    uint4* dst = (uint4*)(h + ((size_t)b * T + t) * 64);
    #pragma unroll
    for (int i = 0; i < 8; ++i) dst[i] = ((const uint4*)pk)[i];
}

// ---------- per-layer kernel (r24-verified math; r25: register diet —
// per-mf GEMM1+gate interleave with packed-bf16 gated regs, no sold
// prefetch (inline skip RMW), W2f/bias2 loaded after bar2. Target:
// VGPR<=64 + 16KB LDS -> 8 blocks/CU so all 2048 blocks fit in ONE
// residency wave per dispatch. ----------
__global__ __launch_bounds__(256) void wn_layer(
    const unsigned short* __restrict__ h_in, unsigned short* __restrict__ h_out,
    unsigned short* __restrict__ skip_sum,
    const unsigned short* __restrict__ pW1, const unsigned short* __restrict__ pW2,
    const float* __restrict__ pB1, const float* __restrict__ pB2,
    int d, int T, int accum)
{
    __shared__ unsigned short Xs[64 * 128];  // 16KB; ch0-7 shifted (later gated), ch8-15 current

    const int tx = threadIdx.x;
    const int w = tx >> 6;
    const int l = tx & 63;
    const int lr = l & 15;
    const int lg = l >> 4;
    const int b = blockIdx.y;
    const int t0 = blockIdx.x * TTILE;
    const size_t bT = (size_t)b * T;
    const int gc = w * 16 + lr;
    const int ghi = gc >> 3;
    const int glo = (gc & 7) << 1;

    // ---- stage ----
    #pragma unroll
    for (int q = 0; q < 4; ++q) {
        int idx = tx * 4 + q;
        int t = idx >> 4;
        int ch = idx & 15;
        int tt = (ch < 8) ? (t0 + t - d) : (t0 + t);
        bf16x8 v = {0, 0, 0, 0, 0, 0, 0, 0};
        if (tt >= 0)
            v = *(const bf16x8*)(h_in + ((size_t)(bT + tt)) * 64 + (ch & 7) * 8);
        int swz = (ch & 8) | ((ch & 7) ^ (t & 7));
        *(bf16x8*)&Xs[(t * 256 + swz * 16) >> 1] = v;
    }

    bf16x8 W1f[2][4];
    #pragma unroll
    for (int nf = 0; nf < 2; ++nf)
        #pragma unroll
        for (int ks = 0; ks < 4; ++ks)
            W1f[nf][ks] = *(const bf16x8*)&pW1[((size_t)(w * 8 + nf * 4 + ks) * 64 + l) * 8];
    float bias1_0 = pB1[w * 32 + lr];
    float bias1_1 = pB1[w * 32 + 16 + lr];

    __syncthreads();   // bar1: staging complete

    // ---- GEMM1 + gate, per-mf (acc pair lives only within one mf) ----
    unsigned int gpk[8];   // 16 gated values packed as bf16 pairs
    #pragma unroll
    for (int mf = 0; mf < 4; ++mf) {
        f32x4 a0 = {bias1_0, bias1_0, bias1_0, bias1_0};
        f32x4 a1 = {bias1_1, bias1_1, bias1_1, bias1_1};
        #pragma unroll
        for (int ks = 0; ks < 4; ++ks) {
            int tr = mf * 16 + lr;
            int chunk = ks * 4 + lg;
            int swz = (chunk & 8) | ((chunk & 7) ^ (tr & 7));
            bf16x8 av = *(const bf16x8*)&Xs[(tr * 256 + swz * 16) >> 1];
            a0 = __builtin_amdgcn_mfma_f32_16x16x32_bf16(av, W1f[0][ks], a0, 0, 0, 0);
            a1 = __builtin_amdgcn_mfma_f32_16x16x32_bf16(av, W1f[1][ks], a1, 0, 0, 0);
        }
        #pragma unroll
        for (int rp = 0; rp < 2; ++rp) {
            unsigned int pk = 0;
            #pragma unroll
            for (int h2 = 0; h2 < 2; ++h2) {
                int r = rp * 2 + h2;
                float e2 = __expf(-2.f * a0[r]);
                float e3 = __expf(-a1[r]);
                float g = (1.f - e2) * __builtin_amdgcn_rcpf((1.f + e2) * (1.f + e3));
                pk |= ((unsigned int)f2bf(g)) << (h2 * 16);
            }
            gpk[mf * 2 + rp] = pk;
        }
    }

    __syncthreads();   // bar2: all GEMM1 reads of shifted half done

    // ---- write gated tile into Xs chunks 0-7 (dead region) ----
    #pragma unroll
    for (int i = 0; i < 16; ++i) {
        int row = (i >> 2) * 16 + lg * 4 + (i & 3);
        int byte = row * 256 + ((ghi ^ (row & 7)) << 4) + glo;
        Xs[byte >> 1] = (unsigned short)(gpk[i >> 1] >> ((i & 1) * 16));
    }

    // load W2 fragments + bias2 now (overlaps Gs writes; not live earlier)
    bf16x8 W2f[2][2];
    #pragma unroll
    for (int nf = 0; nf < 2; ++nf)
        #pragma unroll
        for (int ks = 0; ks < 2; ++ks)
            W2f[nf][ks] = *(const bf16x8*)&pW2[((size_t)(w * 4 + nf * 2 + ks) * 64 + l) * 8];
    float bias2_0 = pB2[w * 32 + lr];
    float bias2_1 = pB2[w * 32 + 16 + lr];

    __syncthreads();   // bar3: gated tile visible

    // ---- GEMM2 + epilogue per-mf, skip RMW inline ----
    #pragma unroll
    for (int mf = 0; mf < 4; ++mf) {
        int tr0 = mf * 16 + lr;
        f32x4 a0 = {bias2_0, bias2_0, bias2_0, bias2_0};
        f32x4 a1 = {bias2_1, bias2_1, bias2_1, bias2_1};
        #pragma unroll
        for (int ks = 0; ks < 2; ++ks) {
            int chunk = ks * 4 + lg;
            int swz = chunk ^ (tr0 & 7);
            bf16x8 av = *(const bf16x8*)&Xs[(tr0 * 256 + swz * 16) >> 1];
            a0 = __builtin_amdgcn_mfma_f32_16x16x32_bf16(av, W2f[0][ks], a0, 0, 0, 0);
            a1 = __builtin_amdgcn_mfma_f32_16x16x32_bf16(av, W2f[1][ks], a1, 0, 0, 0);
        }
        #pragma unroll
        for (int r = 0; r < 4; ++r) {
            int tr = mf * 16 + lg * 4 + r;
            int chunk = 8 | (ghi ^ (tr & 7));
            unsigned short hb = Xs[(tr * 256 + chunk * 16 + glo) >> 1];
            float hres = bf2f(hb) + a0[r];
            size_t gidx = (bT + t0 + tr) * 64 + gc;
            h_out[gidx] = f2bf(hres);
            float base = accum ? bf2f(skip_sum[gidx]) : 0.f;
            skip_sum[gidx] = f2bf(base + a1[r]);
        }
    }
}

// ---------- end: out = end2( relu(end1(skA + skB)) ), dual bf16 skip buffers ----------
__global__ __launch_bounds__(256) void wn_end(
    const unsigned short* __restrict__ skA, const unsigned short* __restrict__ skB,
    const float* __restrict__ w1, const float* __restrict__ b1,
    const float* __restrict__ w2, const float* __restrict__ b2,
    float* __restrict__ out, int T)
{
    int t = blockIdx.x * blockDim.x + threadIdx.x;
    int b = blockIdx.y;
    const unsigned short* rowA = skA + ((size_t)b * T + t) * 64;
    const unsigned short* rowB = skB + ((size_t)b * T + t) * 64;
    float sv[SC];
    #pragma unroll
    for (int k = 0; k < SC; k += 8) {
        bf16x8 va = *(const bf16x8*)&rowA[k];
        bf16x8 vb = *(const bf16x8*)&rowB[k];
        #pragma unroll
        for (int j = 0; j < 8; ++j)
            sv[k + j] = bf2f((unsigned short)va[j]) + bf2f((unsigned short)vb[j]);
    }
    float acc = b2[0];
    for (int c = 0; c < SC; ++c) {
        float s = b1[c];
        #pragma unroll
        for (int k = 0; k < SC; k += 4) {
            float4 wv = *(const float4*)&w1[(size_t)c * SC + k];
            s = fmaf(wv.x, sv[k], fmaf(wv.y, sv[k + 1], fmaf(wv.z, sv[k + 2], fmaf(wv.w, sv[k + 3], s))));
        }
        acc = fmaf(w2[c], fmaxf(s, 0.f), acc);
    }
    out[(size_t)b * T + t] = acc;
}

extern "C" void kernel_launch(void* const* d_in, const int* in_sizes, int n_in,
                              void* d_out, int out_size, void* d_ws, size_t ws_size,
                              hipStream_t stream)
{
    const float* x   = (const float*)d_in[0];
    const float* stw = (const float*)d_in[1];
    const float* stb = (const float*)d_in[2];
    const float* dw  = (const float*)d_in[3];
    const float* db  = (const float*)d_in[4];
    const float* rw  = (const float*)d_in[5];
    const float* rb  = (const float*)d_in[6];
    const float* skw = (const float*)d_in[7];
    const float* skb = (const float*)d_in[8];
    const float* e1w = (const float*)d_in[9];
    const float* e1b = (const float*)d_in[10];
    const float* e2w = (const float*)d_in[11];
    const float* e2b = (const float*)d_in[12];

    const int T = 32768;
    const int B = in_sizes[0] / T;

    char* ws = (char*)d_ws;
    const size_t hbytes = (size_t)B * T * 64 * 2;      // bf16 h / bf16 skip, 16.8 MB each
    unsigned short* h0  = (unsigned short*)ws;
    unsigned short* h1  = (unsigned short*)(ws + hbytes);
    unsigned short* skA = (unsigned short*)(ws + 2 * hbytes);  // layers 0-14
    unsigned short* skB = skA + (size_t)B * T * 64;            // layers 15-29
    unsigned short* pW1 = (unsigned short*)(ws + 2 * hbytes + (size_t)B * T * 64 * 4);
    unsigned short* pW2 = pW1 + (size_t)NLAYERS * 32 * 64 * 8;
    float* pB1 = (float*)(pW2 + (size_t)NLAYERS * 16 * 64 * 8);
    float* pB2 = pB1 + NLAYERS * 128;

    wn_prep<<<dim3(NLAYERS), 256, 0, stream>>>(dw, rw, skw, db, rb, skb, pW1, pW2, pB1, pB2);
    wn_start<<<dim3(T / 256, B), 256, 0, stream>>>(x, stw, stb, h0, T);

    const unsigned short* hin = h0;
    unsigned short* hout = h1;
    for (int i = 0; i < NLAYERS; ++i) {
        int d = 1 << (i % 10);
        unsigned short* skbuf = (i < 15) ? skA : skB;     // two 15-layer chains
        int accum = (i == 0 || i == 15) ? 0 : 1;
        wn_layer<<<dim3(T / TTILE, B), 256, 0, stream>>>(
            hin, hout, skbuf,
            pW1 + (size_t)i * 32 * 64 * 8, pW2 + (size_t)i * 16 * 64 * 8,
            pB1 + i * 128, pB2 + i * 128,
            d, T, accum);
        const unsigned short* tmp = hout;
        hout = (unsigned short*)hin;
        hin = tmp;
    }

    wn_end<<<dim3(T / 256, B), 256, 0, stream>>>(skA, skB, e1w, e1b, e2w, e2b, (float*)d_out, T);
}

// Round 29
// 676.568 us; speedup vs baseline: 1.2341x; 1.2341x over previous
//
#include <hip/hip_runtime.h>
#include <hip/hip_bf16.h>

#define RC 64
#define SC 64
#define NLAYERS 30
#define TTILE 64

typedef __attribute__((ext_vector_type(8))) short bf16x8;
typedef __attribute__((ext_vector_type(4))) float f32x4;

__device__ __forceinline__ unsigned short f2bf(float f) {
    __hip_bfloat16 h = __float2bfloat16(f);
    return *reinterpret_cast<unsigned short*>(&h);
}
__device__ __forceinline__ float bf2f(unsigned short u) {
    unsigned int x = ((unsigned int)u) << 16;
    return *reinterpret_cast<float*>(&x);
}

// ---------- prep: gather weights into bf16 fragment-linear layout (verified r6) ----------
__global__ __launch_bounds__(256) void wn_prep(
    const float* __restrict__ dw, const float* __restrict__ rw,
    const float* __restrict__ skw, const float* __restrict__ db,
    const float* __restrict__ rb, const float* __restrict__ skb,
    unsigned short* __restrict__ pW1, unsigned short* __restrict__ pW2,
    float* __restrict__ pB1, float* __restrict__ pB2)
{
    const int i = blockIdx.x;
    const int tx = threadIdx.x;
    const int l = tx & 63;

    #pragma unroll
    for (int p = 0; p < 8; ++p) {
        int f = p * 4 + (tx >> 6);
        int w = f >> 3, nf = (f >> 2) & 1, ks = f & 3;
        int cpp = w * 32 + nf * 16 + (l & 15);
        int bb = cpp >> 4;
        int c1 = (bb & 1 ? 64 : 0) + (bb >> 1) * 16 + (cpp & 15);
        bf16x8 v;
        #pragma unroll
        for (int j = 0; j < 8; ++j) {
            int k = ks * 32 + (l >> 4) * 8 + j;
            int tap = (k < 64) ? 0 : 1;
            int kk = k & 63;
            v[j] = (short)f2bf(dw[(((size_t)i * 128 + c1) * 64 + kk) * 2 + tap]);
        }
        *(bf16x8*)&pW1[((size_t)(i * 32 + f) * 64 + l) * 8] = v;
    }

    #pragma unroll
    for (int p = 0; p < 4; ++p) {
        int f = p * 4 + (tx >> 6);
        int w = f >> 2, nf = (f >> 1) & 1, ks = f & 1;
        int cpp = w * 32 + nf * 16 + (l & 15);
        int bb = cpp >> 4;
        int c2 = (bb >> 1) * 16 + (cpp & 15);
        const float* src = (bb & 1) ? skw : rw;
        bf16x8 v;
        #pragma unroll
        for (int j = 0; j < 8; ++j) {
            int k = ks * 32 + (l >> 4) * 8 + j;
            v[j] = (short)f2bf(src[((size_t)i * 64 + c2) * 64 + k]);
        }
        *(bf16x8*)&pW2[((size_t)(i * 16 + f) * 64 + l) * 8] = v;
    }

    if (tx < 128) {
        int bb = tx >> 4, r = tx & 15;
        int c1 = (bb & 1 ? 64 : 0) + (bb >> 1) * 16 + r;
        pB1[i * 128 + tx] = db[i * 128 + c1];
        int c2 = (bb >> 1) * 16 + r;
        pB2[i * 128 + tx] = (bb & 1) ? skb[i * 64 + c2] : rb[i * 64 + c2];
    }
}

// ---------- start: h[b][t][c] bf16 t-major ----------
__global__ __launch_bounds__(256) void wn_start(
    const float* __restrict__ x, const float* __restrict__ sw,
    const float* __restrict__ sb, unsigned short* __restrict__ h, int T)
{
    int t = blockIdx.x * blockDim.x + threadIdx.x;
    int b = blockIdx.y;
    float xv = x[(size_t)b * T + t];
    unsigned int pk[32];
    #pragma unroll
    for (int c = 0; c < 64; c += 2) {
        float v0 = fmaf(sw[c], xv, sb[c]);
        float v1 = fmaf(sw[c + 1], xv, sb[c + 1]);
        pk[c >> 1] = (unsigned int)f2bf(v0) | ((unsigned int)f2bf(v1) << 16);
    }
    uint4* dst = (uint4*)(h + ((size_t)b * T + t) * 64);
    #pragma unroll
    for (int i = 0; i < 8; ++i) dst[i] = ((const uint4*)pk)[i];
}

// ---------- per-layer kernel (r22-VERIFIED configuration: clustered GEMM1,
// separate Gs, sold prefetch, 2 barriers — 677us total, session best) ----------
__global__ __launch_bounds__(256) void wn_layer(
    const unsigned short* __restrict__ h_in, unsigned short* __restrict__ h_out,
    unsigned short* __restrict__ skip_sum,
    const unsigned short* __restrict__ pW1, const unsigned short* __restrict__ pW2,
    const float* __restrict__ pB1, const float* __restrict__ pB2,
    int d, int T, int accum)
{
    __shared__ unsigned short Xs[64 * 128];
    __shared__ unsigned short Gs[64 * 64];

    const int tx = threadIdx.x;
    const int w = tx >> 6;
    const int l = tx & 63;
    const int lr = l & 15;
    const int lg = l >> 4;
    const int b = blockIdx.y;
    const int t0 = blockIdx.x * TTILE;
    const size_t bT = (size_t)b * T;

    #pragma unroll
    for (int q = 0; q < 4; ++q) {
        int idx = tx * 4 + q;
        int t = idx >> 4;
        int ch = idx & 15;
        int tt = (ch < 8) ? (t0 + t - d) : (t0 + t);
        bf16x8 v = {0, 0, 0, 0, 0, 0, 0, 0};
        if (tt >= 0)
            v = *(const bf16x8*)(h_in + ((size_t)(bT + tt)) * 64 + (ch & 7) * 8);
        int swz = (ch & 8) | ((ch & 7) ^ (t & 7));
        *(bf16x8*)&Xs[(t * 256 + swz * 16) >> 1] = v;
    }

    bf16x8 W1f[2][4];
    #pragma unroll
    for (int nf = 0; nf < 2; ++nf)
        #pragma unroll
        for (int ks = 0; ks < 4; ++ks)
            W1f[nf][ks] = *(const bf16x8*)&pW1[((size_t)(w * 8 + nf * 4 + ks) * 64 + l) * 8];
    bf16x8 W2f[2][2];
    #pragma unroll
    for (int nf = 0; nf < 2; ++nf)
        #pragma unroll
        for (int ks = 0; ks < 2; ++ks)
            W2f[nf][ks] = *(const bf16x8*)&pW2[((size_t)(w * 4 + nf * 2 + ks) * 64 + l) * 8];

    float bias1[2], bias2[2];
    #pragma unroll
    for (int nf = 0; nf < 2; ++nf) {
        bias1[nf] = pB1[w * 32 + nf * 16 + lr];
        bias2[nf] = pB2[w * 32 + nf * 16 + lr];
    }

    __syncthreads();

    f32x4 acc1[4][2];
    #pragma unroll
    for (int mf = 0; mf < 4; ++mf) {
        #pragma unroll
        for (int nf = 0; nf < 2; ++nf) {
            f32x4 a = {bias1[nf], bias1[nf], bias1[nf], bias1[nf]};
            #pragma unroll
            for (int ks = 0; ks < 4; ++ks) {
                int tr = mf * 16 + lr;
                int chunk = ks * 4 + lg;
                int swz = (chunk & 8) | ((chunk & 7) ^ (tr & 7));
                bf16x8 av = *(const bf16x8*)&Xs[(tr * 256 + swz * 16) >> 1];
                a = __builtin_amdgcn_mfma_f32_16x16x32_bf16(av, W1f[nf][ks], a, 0, 0, 0);
            }
            acc1[mf][nf] = a;
        }
    }

    const int gc = w * 16 + lr;
    #pragma unroll
    for (int mf = 0; mf < 4; ++mf) {
        #pragma unroll
        for (int r = 0; r < 4; ++r) {
            int tr = mf * 16 + lg * 4 + r;
            float e2 = __expf(-2.f * acc1[mf][0][r]);
            float e3 = __expf(-acc1[mf][1][r]);
            float gated = (1.f - e2) * __builtin_amdgcn_rcpf((1.f + e2) * (1.f + e3));
            int byte = tr * 128 + (((gc >> 3) ^ (tr & 7)) * 16) + (gc & 7) * 2;
            Gs[byte >> 1] = f2bf(gated);
        }
    }

    float sold[16];
    if (accum) {
        #pragma unroll
        for (int mf = 0; mf < 4; ++mf)
            #pragma unroll
            for (int r = 0; r < 4; ++r) {
                int tr = mf * 16 + lg * 4 + r;
                sold[mf * 4 + r] = bf2f(skip_sum[(bT + t0 + tr) * 64 + gc]);
            }
    } else {
        #pragma unroll
        for (int i = 0; i < 16; ++i) sold[i] = 0.f;
    }

    __syncthreads();

    f32x4 acc2[4][2];
    #pragma unroll
    for (int mf = 0; mf < 4; ++mf) {
        #pragma unroll
        for (int nf = 0; nf < 2; ++nf) {
            f32x4 a = {bias2[nf], bias2[nf], bias2[nf], bias2[nf]};
            #pragma unroll
            for (int ks = 0; ks < 2; ++ks) {
                int tr = mf * 16 + lr;
                int chunk = ks * 4 + lg;
                int swz = chunk ^ (tr & 7);
                bf16x8 av = *(const bf16x8*)&Gs[(tr * 128 + swz * 16) >> 1];
                a = __builtin_amdgcn_mfma_f32_16x16x32_bf16(av, W2f[nf][ks], a, 0, 0, 0);
            }
            acc2[mf][nf] = a;
        }
    }

    #pragma unroll
    for (int mf = 0; mf < 4; ++mf) {
        #pragma unroll
        for (int r = 0; r < 4; ++r) {
            int tr = mf * 16 + lg * 4 + r;
            int chunk = 8 | ((gc >> 3) ^ (tr & 7));
            unsigned short hb = Xs[(tr * 256 + chunk * 16 + (gc & 7) * 2) >> 1];
            float hres = bf2f(hb) + acc2[mf][0][r];
            size_t gidx = (bT + t0 + tr) * 64 + gc;
            h_out[gidx] = f2bf(hres);
            skip_sum[gidx] = f2bf(sold[mf * 4 + r] + acc2[mf][1][r]);
        }
    }
}

// ---------- end: out = end2( relu(end1(skA + skB)) ), dual bf16 skip buffers ----------
__global__ __launch_bounds__(256) void wn_end(
    const unsigned short* __restrict__ skA, const unsigned short* __restrict__ skB,
    const float* __restrict__ w1, const float* __restrict__ b1,
    const float* __restrict__ w2, const float* __restrict__ b2,
    float* __restrict__ out, int T)
{
    int t = blockIdx.x * blockDim.x + threadIdx.x;
    int b = blockIdx.y;
    const unsigned short* rowA = skA + ((size_t)b * T + t) * 64;
    const unsigned short* rowB = skB + ((size_t)b * T + t) * 64;
    float sv[SC];
    #pragma unroll
    for (int k = 0; k < SC; k += 8) {
        bf16x8 va = *(const bf16x8*)&rowA[k];
        bf16x8 vb = *(const bf16x8*)&rowB[k];
        #pragma unroll
        for (int j = 0; j < 8; ++j)
            sv[k + j] = bf2f((unsigned short)va[j]) + bf2f((unsigned short)vb[j]);
    }
    float acc = b2[0];
    for (int c = 0; c < SC; ++c) {
        float s = b1[c];
        #pragma unroll
        for (int k = 0; k < SC; k += 4) {
            float4 wv = *(const float4*)&w1[(size_t)c * SC + k];
            s = fmaf(wv.x, sv[k], fmaf(wv.y, sv[k + 1], fmaf(wv.z, sv[k + 2], fmaf(wv.w, sv[k + 3], s))));
        }
        acc = fmaf(w2[c], fmaxf(s, 0.f), acc);
    }
    out[(size_t)b * T + t] = acc;
}

extern "C" void kernel_launch(void* const* d_in, const int* in_sizes, int n_in,
                              void* d_out, int out_size, void* d_ws, size_t ws_size,
                              hipStream_t stream)
{
    const float* x   = (const float*)d_in[0];
    const float* stw = (const float*)d_in[1];
    const float* stb = (const float*)d_in[2];
    const float* dw  = (const float*)d_in[3];
    const float* db  = (const float*)d_in[4];
    const float* rw  = (const float*)d_in[5];
    const float* rb  = (const float*)d_in[6];
    const float* skw = (const float*)d_in[7];
    const float* skb = (const float*)d_in[8];
    const float* e1w = (const float*)d_in[9];
    const float* e1b = (const float*)d_in[10];
    const float* e2w = (const float*)d_in[11];
    const float* e2b = (const float*)d_in[12];

    const int T = 32768;
    const int B = in_sizes[0] / T;

    char* ws = (char*)d_ws;
    const size_t hbytes = (size_t)B * T * 64 * 2;      // bf16 h / bf16 skip, 16.8 MB each
    unsigned short* h0  = (unsigned short*)ws;
    unsigned short* h1  = (unsigned short*)(ws + hbytes);
    unsigned short* skA = (unsigned short*)(ws + 2 * hbytes);  // layers 0-14
    unsigned short* skB = skA + (size_t)B * T * 64;            // layers 15-29
    unsigned short* pW1 = (unsigned short*)(ws + 2 * hbytes + (size_t)B * T * 64 * 4);
    unsigned short* pW2 = pW1 + (size_t)NLAYERS * 32 * 64 * 8;
    float* pB1 = (float*)(pW2 + (size_t)NLAYERS * 16 * 64 * 8);
    float* pB2 = pB1 + NLAYERS * 128;

    wn_prep<<<dim3(NLAYERS), 256, 0, stream>>>(dw, rw, skw, db, rb, skb, pW1, pW2, pB1, pB2);
    wn_start<<<dim3(T / 256, B), 256, 0, stream>>>(x, stw, stb, h0, T);

    const unsigned short* hin = h0;
    unsigned short* hout = h1;
    for (int i = 0; i < NLAYERS; ++i) {
        int d = 1 << (i % 10);
        unsigned short* skbuf = (i < 15) ? skA : skB;     // two 15-layer chains
        int accum = (i == 0 || i == 15) ? 0 : 1;
        wn_layer<<<dim3(T / TTILE, B), 256, 0, stream>>>(
            hin, hout, skbuf,
            pW1 + (size_t)i * 32 * 64 * 8, pW2 + (size_t)i * 16 * 64 * 8,
            pB1 + i * 128, pB2 + i * 128,
            d, T, accum);
        const unsigned short* tmp = hout;
        hout = (unsigned short*)hin;
        hin = tmp;
    }

    wn_end<<<dim3(T / 256, B), 256, 0, stream>>>(skA, skB, e1w, e1b, e2w, e2b, (float*)d_out, T);
}